// Round 11
// baseline (759.651 us; speedup 1.0000x reference)
//
#include <hip/hip_runtime.h>

#define NN 10000
#define EE 320000
#define ET (EE + NN)      // 330000 edges incl self-loops
#define FIN 256
#define HD 128
#define NEG 0.2f
#define NB 1024           // == 256 CUs x 4 blocks/CU (co-resident by launch_bounds)
#define NT 256
#define GT (NB * NT)
#define NG 1250           // node groups of 8

// Inputs fp32, edge_index int32, OUTPUT fp32.

struct GatP {
    const float* x; const int* ei;
    const float* W1; const float* as1; const float* ad1; const float* b1;
    const float* W2; const float* as2; const float* ad2; const float* b2;
    const float* Wr; const float* br; const float* Wc; const float* bc;
    float* out;
    float* h1; float* h2; float* sA1; float* dA1; float* sA2; float* dA2;
    int* counts; int* cnt; int* flag; int* offsets; int* cursor; int* srclist;
};

// Coherent (agent-scope, relaxed) stores: bypass the non-coherent per-XCD L2,
// land at the coherence point (LLC). This removes the need for any wbl2 in the
// barrier — round 10's ~90us/barrier was release-wbl2 + same-line arrival RMWs.
__device__ __forceinline__ void st1f(float* d, float v) {
    __hip_atomic_store(d, v, __ATOMIC_RELAXED, __HIP_MEMORY_SCOPE_AGENT);
}
__device__ __forceinline__ void st1i(int* d, int v) {
    __hip_atomic_store(d, v, __ATOMIC_RELAXED, __HIP_MEMORY_SCOPE_AGENT);
}
__device__ __forceinline__ void st2f(float* d, float2 v) {
    unsigned long long u;
    __builtin_memcpy(&u, &v, 8);
    __hip_atomic_store((unsigned long long*)d, u, __ATOMIC_RELAXED, __HIP_MEMORY_SCOPE_AGENT);
}

// Grid barrier: relaxed arrivals spread over 64 padded counters (16 blocks
// each); block 0 wave 0 ballots the counters and publishes phase to flag;
// everyone else polls flag relaxed. One acquire fence (L2 inv) per block on
// exit. __syncthreads' vmcnt(0) drain orders prior (coherent) stores before
// the arrival. Bounded spins: fail loud, never hang.
__device__ __forceinline__ void gbar(int* cnt, int* flag, int phase) {
    __syncthreads();
    const int t = threadIdx.x;
    const int b = blockIdx.x;
    if (b == 0) {
        if (t < 64) {
            if (t == 0)
                __hip_atomic_fetch_add(&cnt[0], 1, __ATOMIC_RELAXED, __HIP_MEMORY_SCOPE_AGENT);
            int spins = 0;
            for (;;) {
                int v = __hip_atomic_load(&cnt[t * 16], __ATOMIC_RELAXED, __HIP_MEMORY_SCOPE_AGENT);
                if (__ballot(v >= 16 * phase) == ~0ull) break;
                __builtin_amdgcn_s_sleep(4);
                if (++spins > 3000000) break;
            }
            if (t == 0)
                __hip_atomic_store(flag, phase, __ATOMIC_RELAXED, __HIP_MEMORY_SCOPE_AGENT);
        }
    } else if (t == 0) {
        __hip_atomic_fetch_add(&cnt[(b & 63) * 16], 1, __ATOMIC_RELAXED, __HIP_MEMORY_SCOPE_AGENT);
        int spins = 0;
        while (__hip_atomic_load(flag, __ATOMIC_RELAXED, __HIP_MEMORY_SCOPE_AGENT) < phase) {
            __builtin_amdgcn_s_sleep(4);
            if (++spins > 3000000) break;
        }
    }
    if (t == 0) __builtin_amdgcn_fence(__ATOMIC_ACQUIRE, "agent");
    __syncthreads();
}

__device__ __forceinline__ float edge_w(float as_v, float adn) {
    float e = as_v + adn;
    e = (e > 0.f) ? e : NEG * e;
    return __expf(e);
}

__global__ __launch_bounds__(NT, 4) void k_fused(GatP p) {
    __shared__ float xs[8192];   // 32 KB, reused per phase
    const int t = threadIdx.x;
    const int b = blockIdx.x;
    const int gtid = b * NT + t;

    // ================= P1: gemm1 (h1, sA1, dA1) + hist + out seed =================
    {
        int g4 = t >> 6, tt = t & 63, f = tt * 2;
        int ng = b + NB * g4;                     // groups 0..1249 over 4096 slots
        if (ng < NG) {
            float* xw = xs + g4 * 2048;           // own wave slice: no syncthreads
            float4* xw4 = (float4*)xw;
            const float4* xv = (const float4*)(p.x + (size_t)ng * 8 * FIN);
            #pragma unroll
            for (int i = 0; i < 8; i++) xw4[tt + 64 * i] = xv[tt + 64 * i];
            float2 acc[8];
            #pragma unroll
            for (int m = 0; m < 8; m++) acc[m] = make_float2(0.f, 0.f);
            for (int k = 0; k < FIN; k += 4) {
                float2 w0 = *(const float2*)&p.W1[(k + 0) * HD + f];
                float2 w1 = *(const float2*)&p.W1[(k + 1) * HD + f];
                float2 w2 = *(const float2*)&p.W1[(k + 2) * HD + f];
                float2 w3 = *(const float2*)&p.W1[(k + 3) * HD + f];
                #pragma unroll
                for (int m = 0; m < 8; m++) {
                    float4 xk = *(const float4*)&xw[m * FIN + k];
                    acc[m].x += xk.x * w0.x; acc[m].y += xk.x * w0.y;
                    acc[m].x += xk.y * w1.x; acc[m].y += xk.y * w1.y;
                    acc[m].x += xk.z * w2.x; acc[m].y += xk.z * w2.y;
                    acc[m].x += xk.w * w3.x; acc[m].y += xk.w * w3.y;
                }
            }
            float2 ats = *(const float2*)&p.as1[f];
            float2 atd = *(const float2*)&p.ad1[f];
            #pragma unroll
            for (int m = 0; m < 8; m++) {
                int node = ng * 8 + m;
                st2f(&p.h1[(size_t)node * HD + f], acc[m]);
                float vs = acc[m].x * ats.x + acc[m].y * ats.y;
                float vd = acc[m].x * atd.x + acc[m].y * atd.y;
                #pragma unroll
                for (int off = 32; off > 0; off >>= 1) {
                    vs += __shfl_down(vs, off);
                    vd += __shfl_down(vd, off);
                }
                if (tt == 0) { st1f(&p.sA1[node], vs); st1f(&p.dA1[node], vd); }
            }
        }
    }
    for (int i = gtid; i < ET; i += GT) {
        int d = (i < EE) ? p.ei[EE + i] : (i - EE);
        atomicAdd(&p.counts[d], 1);
    }
    if (gtid == 0) { st1f(&p.out[0], p.bc[0]); st1f(&p.out[1], p.bc[1]); }
    gbar(p.cnt, p.flag, 1);

    // ================= P2: scan counts -> offsets/cursor (block 0) =================
    if (b == 0) {
        const int CHUNK = 40;   // 256*40 = 10240 >= 10000
        int* sm = (int*)xs;
        int base = t * CHUNK;
        int s = 0;
        for (int i = 0; i < CHUNK; i++) {
            int idx = base + i;
            if (idx < NN) s += p.counts[idx];
        }
        sm[t] = s;
        __syncthreads();
        for (int off = 1; off < NT; off <<= 1) {
            int v = (t >= off) ? sm[t - off] : 0;
            __syncthreads();
            sm[t] += v;
            __syncthreads();
        }
        int run = (t > 0) ? sm[t - 1] : 0;
        for (int i = 0; i < CHUNK; i++) {
            int idx = base + i;
            if (idx < NN) {
                st1i(&p.offsets[idx], run);
                st1i(&p.cursor[idx], run);
                run += p.counts[idx];
            }
        }
        if (t == NT - 1) st1i(&p.offsets[NN], sm[NT - 1]);
    }
    gbar(p.cnt, p.flag, 2);

    // ================= P3: scatter source ids into CSR =================
    for (int i = gtid; i < ET; i += GT) {
        int s, d;
        if (i < EE) { s = p.ei[i]; d = p.ei[EE + i]; }
        else        { s = i - EE; d = s; }
        int pos = atomicAdd(&p.cursor[d], 1);
        st1i(&p.srclist[pos], s);
    }
    gbar(p.cnt, p.flag, 3);

    // ========== P4: agg1 (8-node group -> LDS) fused with gemm2 (-> h2, sA2, dA2) ==========
    {
        int wv = t >> 6, l = t & 63, f = l * 2;
        const float2* h1v = (const float2*)p.h1;
        for (int g = b; g < NG; g += NB) {
            #pragma unroll
            for (int r = 0; r < 2; r++) {
                int node = g * 8 + 2 * wv + r;
                int beg = p.offsets[node], end = p.offsets[node + 1];
                float adn = p.dA1[node];
                float ax = 0.f, ay = 0.f, z = 0.f;
                int pp = beg;
                for (; pp + 4 <= end; pp += 4) {
                    int s0 = p.srclist[pp],     s1 = p.srclist[pp + 1];
                    int s2 = p.srclist[pp + 2], s3 = p.srclist[pp + 3];
                    float2 h0 = h1v[(size_t)s0 * 64 + l];
                    float2 h1x = h1v[(size_t)s1 * 64 + l];
                    float2 hh = h1v[(size_t)s2 * 64 + l];
                    float2 h3 = h1v[(size_t)s3 * 64 + l];
                    float w0 = edge_w(p.sA1[s0], adn);
                    float w1 = edge_w(p.sA1[s1], adn);
                    float w2 = edge_w(p.sA1[s2], adn);
                    float w3 = edge_w(p.sA1[s3], adn);
                    z += (w0 + w1) + (w2 + w3);
                    ax += w0 * h0.x + w1 * h1x.x + w2 * hh.x + w3 * h3.x;
                    ay += w0 * h0.y + w1 * h1x.y + w2 * hh.y + w3 * h3.y;
                }
                for (; pp < end; pp++) {
                    int s = p.srclist[pp];
                    float2 hv = h1v[(size_t)s * 64 + l];
                    float ww = edge_w(p.sA1[s], adn);
                    z += ww;
                    ax += ww * hv.x;
                    ay += ww * hv.y;
                }
                float2 bb = *(const float2*)&p.b1[f];
                float ox = ax / z + bb.x, oy = ay / z + bb.y;
                ox = (ox > 0.f) ? ox : 0.f;
                oy = (oy > 0.f) ? oy : 0.f;
                *(float2*)&xs[(2 * wv + r) * HD + f] = make_float2(ox, oy);
            }
            __syncthreads();
            // gemm2 on the 8 LDS rows: wave wv owns m = 2wv, 2wv+1
            float2 acc[2];
            acc[0] = make_float2(0.f, 0.f);
            acc[1] = make_float2(0.f, 0.f);
            for (int k = 0; k < HD; k += 4) {
                float2 w0 = *(const float2*)&p.W2[(k + 0) * HD + f];
                float2 w1 = *(const float2*)&p.W2[(k + 1) * HD + f];
                float2 w2 = *(const float2*)&p.W2[(k + 2) * HD + f];
                float2 w3 = *(const float2*)&p.W2[(k + 3) * HD + f];
                #pragma unroll
                for (int mi = 0; mi < 2; mi++) {
                    float4 xk = *(const float4*)&xs[(2 * wv + mi) * HD + k];
                    acc[mi].x += xk.x * w0.x; acc[mi].y += xk.x * w0.y;
                    acc[mi].x += xk.y * w1.x; acc[mi].y += xk.y * w1.y;
                    acc[mi].x += xk.z * w2.x; acc[mi].y += xk.z * w2.y;
                    acc[mi].x += xk.w * w3.x; acc[mi].y += xk.w * w3.y;
                }
            }
            float2 ats = *(const float2*)&p.as2[f];
            float2 atd = *(const float2*)&p.ad2[f];
            #pragma unroll
            for (int mi = 0; mi < 2; mi++) {
                int node = g * 8 + 2 * wv + mi;
                st2f(&p.h2[(size_t)node * HD + f], acc[mi]);
                float vs = acc[mi].x * ats.x + acc[mi].y * ats.y;
                float vd = acc[mi].x * atd.x + acc[mi].y * atd.y;
                #pragma unroll
                for (int off = 32; off > 0; off >>= 1) {
                    vs += __shfl_down(vs, off);
                    vd += __shfl_down(vd, off);
                }
                if (l == 0) { st1f(&p.sA2[node], vs); st1f(&p.dA2[node], vd); }
            }
            __syncthreads();   // xs reused next g iteration
        }
    }
    gbar(p.cnt, p.flag, 4);

    // ================= P5: agg2 + reduce_dim + classifier =================
    {
        int wv = t >> 6, l = t & 63, f = l * 2;
        const float2* h2v = (const float2*)p.h2;
        float br0 = p.br[0];
        float c0 = 0.f, c1 = 0.f;            // lane-0-only classifier partials
        for (int node = (b << 2) + wv; node < NN; node += NB * 4) {
            int beg = p.offsets[node], end = p.offsets[node + 1];
            float adn = p.dA2[node];
            float ax = 0.f, ay = 0.f, z = 0.f;
            int pp = beg;
            for (; pp + 4 <= end; pp += 4) {
                int s0 = p.srclist[pp],     s1 = p.srclist[pp + 1];
                int s2 = p.srclist[pp + 2], s3 = p.srclist[pp + 3];
                float2 h0 = h2v[(size_t)s0 * 64 + l];
                float2 h1x = h2v[(size_t)s1 * 64 + l];
                float2 hh = h2v[(size_t)s2 * 64 + l];
                float2 h3 = h2v[(size_t)s3 * 64 + l];
                float w0 = edge_w(p.sA2[s0], adn);
                float w1 = edge_w(p.sA2[s1], adn);
                float w2 = edge_w(p.sA2[s2], adn);
                float w3 = edge_w(p.sA2[s3], adn);
                z += (w0 + w1) + (w2 + w3);
                ax += w0 * h0.x + w1 * h1x.x + w2 * hh.x + w3 * h3.x;
                ay += w0 * h0.y + w1 * h1x.y + w2 * hh.y + w3 * h3.y;
            }
            for (; pp < end; pp++) {
                int s = p.srclist[pp];
                float2 hv = h2v[(size_t)s * 64 + l];
                float ww = edge_w(p.sA2[s], adn);
                z += ww;
                ax += ww * hv.x;
                ay += ww * hv.y;
            }
            float2 bb = *(const float2*)&p.b2[f];
            float ox = ax / z + bb.x, oy = ay / z + bb.y;
            ox = (ox > 0.f) ? ox : 0.f;
            oy = (oy > 0.f) ? oy : 0.f;
            float2 wr = *(const float2*)&p.Wr[f];
            float part = ox * wr.x + oy * wr.y;
            #pragma unroll
            for (int off = 32; off > 0; off >>= 1) part += __shfl_down(part, off);
            if (l == 0) {
                float rv = part + br0;
                c0 += rv * p.Wc[2 * node];
                c1 += rv * p.Wc[2 * node + 1];
            }
        }
        __syncthreads();
        float* cred = xs;
        if (l == 0) { cred[wv] = c0; cred[4 + wv] = c1; }
        __syncthreads();
        if (t == 0) {
            atomicAdd(&p.out[0], cred[0] + cred[1] + cred[2] + cred[3]);
            atomicAdd(&p.out[1], cred[4] + cred[5] + cred[6] + cred[7]);
        }
    }
}

// ---------------- launch: 1 memset node + 1 kernel node ----------------

extern "C" void kernel_launch(void* const* d_in, const int* in_sizes, int n_in,
                              void* d_out, int out_size, void* d_ws, size_t ws_size,
                              hipStream_t stream) {
    GatP p;
    p.x   = (const float*)d_in[0];
    p.ei  = (const int*)d_in[1];
    p.W1  = (const float*)d_in[2];
    p.as1 = (const float*)d_in[3];
    p.ad1 = (const float*)d_in[4];
    p.b1  = (const float*)d_in[5];
    p.W2  = (const float*)d_in[6];
    p.as2 = (const float*)d_in[7];
    p.ad2 = (const float*)d_in[8];
    p.b2  = (const float*)d_in[9];
    p.Wr  = (const float*)d_in[10];
    p.br  = (const float*)d_in[11];
    p.Wc  = (const float*)d_in[12];
    p.bc  = (const float*)d_in[13];
    p.out = (float*)d_out;

    float* f = (float*)d_ws;
    p.h1  = f;                      f += (size_t)NN * HD;
    p.h2  = f;                      f += (size_t)NN * HD;
    p.sA1 = f;                      f += NN;
    p.dA1 = f;                      f += NN;
    p.sA2 = f;                      f += NN;
    p.dA2 = f;                      f += NN;
    int* ip = (int*)f;
    p.counts  = ip;                 ip += NN;        // ---- memset zeroes from
    p.cnt     = ip;                 ip += 64 * 16;   //      counts through flag
    p.flag    = ip;                 ip += 16;        // ----
    p.offsets = ip;                 ip += NN + 1;
    p.cursor  = ip;                 ip += NN;
    p.srclist = ip;                 ip += ET;

    hipMemsetAsync(p.counts, 0, (NN + 64 * 16 + 16) * sizeof(int), stream);
    k_fused<<<NB, NT, 0, stream>>>(p);
}